// Round 1
// baseline (661.121 us; speedup 1.0000x reference)
//
#include <hip/hip_runtime.h>
#include <math.h>

#define T_STEPS 4096
#define VOCAB   32000
#define NV4     (VOCAB / 4)   // 8000 float4 per row

// Combine rule: strictly-greater wins; on exact tie, smaller group index wins.
// Group order implies element order: g < g'  =>  g*4+c < g'*4+c' for any c,c',
// so first-occurrence argmax is preserved without tracking the component.
__device__ __forceinline__ void comb(float& m, int& g, float om, int og) {
    if (om > m || (om == m && og < g)) { m = om; g = og; }
}

// Deferred-position update: one fmax tree (independent of the accumulator
// chain) + one cmp + 2 cndmask. 6 VALU per 16B instead of 12+.
__device__ __forceinline__ void upd_group(float& m, int& g, float4 a, int j) {
    const float ma = fmaxf(fmaxf(a.x, a.y), fmaxf(a.z, a.w));
    if (ma > m) { m = ma; g = j; }
}

__global__ __launch_bounds__(256, 8) void ctc_argmax_kernel(const float* __restrict__ em,
                                                            int* __restrict__ idx_out) {
    const int t   = blockIdx.x;
    const int tid = threadIdx.x;
    const float4* row4 = (const float4*)(em + (size_t)t * VOCAB);

    // 4 independent (max, group) accumulators -> 4 loads in flight per wave,
    // each with only a 1-deep cmp/cndmask serial chain per iteration.
    float m0 = -INFINITY, m1 = -INFINITY, m2 = -INFINITY, m3 = -INFINITY;
    int   g0 = 0x7fffffff, g1 = 0x7fffffff, g2 = 0x7fffffff, g3 = 0x7fffffff;

    // 7 uniform iterations cover groups [0, 7167]; every thread runs all 7
    // (no per-wave divergent extra iteration like the old j+768<NV4 loop).
    #pragma unroll 1
    for (int it = 0; it < 7; ++it) {
        const int j = tid + it * 1024;
        const float4 a = row4[j];
        const float4 b = row4[j + 256];
        const float4 c = row4[j + 512];
        const float4 d = row4[j + 768];
        upd_group(m0, g0, a, j);
        upd_group(m1, g1, b, j + 256);
        upd_group(m2, g2, c, j + 512);
        upd_group(m3, g3, d, j + 768);
    }
    // Tail: groups [7168, 7999]. Indices stay ascending within each
    // accumulator (last main-loop g per acc <= 7167), keeping ties safe.
    {
        const float4 a = row4[7168 + tid];
        upd_group(m0, g0, a, 7168 + tid);
        const float4 b = row4[7424 + tid];
        upd_group(m1, g1, b, 7424 + tid);
        const float4 c = row4[7680 + tid];
        upd_group(m2, g2, c, 7680 + tid);
        if (tid < 64) {
            const float4 d = row4[7936 + tid];
            upd_group(m3, g3, d, 7936 + tid);
        }
    }

    comb(m0, g0, m1, g1);
    comb(m2, g2, m3, g3);
    comb(m0, g0, m2, g2);

    // 64-lane wave reduction on (max, group)
    #pragma unroll
    for (int off = 32; off > 0; off >>= 1) {
        const float om = __shfl_down(m0, off, 64);
        const int   og = __shfl_down(g0, off, 64);
        comb(m0, g0, om, og);
    }

    __shared__ float sm[4];
    __shared__ int   sg[4];
    const int lane = tid & 63;
    const int wave = tid >> 6;
    if (lane == 0) { sm[wave] = m0; sg[wave] = g0; }
    __syncthreads();
    if (tid == 0) {
        #pragma unroll
        for (int w = 1; w < 4; ++w) comb(m0, g0, sm[w], sg[w]);
        // Resolve the component once per block: one 16B reload + 4 compares.
        // fmaxf returns one of its inputs bit-exactly, so == matches.
        const float4 win = row4[g0];
        const int c = (win.x == m0) ? 0 : (win.y == m0) ? 1 : (win.z == m0) ? 2 : 3;
        idx_out[t] = g0 * 4 + c;
    }
}

__global__ __launch_bounds__(1024) void ctc_compact_kernel(const int* __restrict__ idx,
                                                           int* __restrict__ out) {
    __shared__ int wsum[16];
    const int tid  = threadIdx.x;
    const int base = tid * 4;

    int v[4], keep[4];
    const int prev0 = (base == 0) ? -1 : idx[base - 1];  // sentinel: t=0 always first-of-run
    int cnt = 0;
    #pragma unroll
    for (int k = 0; k < 4; ++k) {
        v[k] = idx[base + k];
        const int p = (k == 0) ? prev0 : v[k - 1];
        keep[k] = (v[k] != p && v[k] != 0) ? 1 : 0;
        cnt += keep[k];
    }

    // inclusive scan of per-thread counts within each 64-lane wave
    const int lane = tid & 63;
    const int wave = tid >> 6;
    int incl = cnt;
    #pragma unroll
    for (int off = 1; off < 64; off <<= 1) {
        int n = __shfl_up(incl, off, 64);
        if (lane >= off) incl += n;
    }
    if (lane == 63) wsum[wave] = incl;

    // fill padded output with -1 (d_out is re-poisoned to 0xAA each call)
    #pragma unroll
    for (int k = 0; k < 4; ++k) out[base + k] = -1;
    __syncthreads();

    // scan the 16 wave totals in wave 0
    if (wave == 0) {
        int s = (lane < 16) ? wsum[lane] : 0;
        #pragma unroll
        for (int off = 1; off < 16; off <<= 1) {
            int n = __shfl_up(s, off, 64);
            if (lane >= off) s += n;
        }
        if (lane < 16) wsum[lane] = s;
    }
    __syncthreads();

    const int waveoff = (wave == 0) ? 0 : wsum[wave - 1];
    int pos = waveoff + incl - cnt;  // exclusive prefix for this thread
    #pragma unroll
    for (int k = 0; k < 4; ++k) {
        if (keep[k]) out[pos++] = v[k];
    }
    if (tid == 0) out[T_STEPS] = wsum[15];  // count
}

extern "C" void kernel_launch(void* const* d_in, const int* in_sizes, int n_in,
                              void* d_out, int out_size, void* d_ws, size_t ws_size,
                              hipStream_t stream) {
    const float* em  = (const float*)d_in[0];
    int*         out = (int*)d_out;          // [4097] int32: padded[4096], count
    int*         idx = (int*)d_ws;           // [4096] int32 scratch

    ctc_argmax_kernel<<<dim3(T_STEPS), dim3(256), 0, stream>>>(em, idx);
    ctc_compact_kernel<<<dim3(1), dim3(1024), 0, stream>>>(idx, out);
}

// Round 3
// 626.247 us; speedup vs baseline: 1.0557x; 1.0557x over previous
//
#include <hip/hip_runtime.h>
#include <math.h>

#define T_STEPS 4096
#define VOCAB   32000
#define NV4     (VOCAB / 4)   // 8000 float4 groups per row

typedef float f32x4 __attribute__((ext_vector_type(4)));

// Combine rule: strictly-greater wins; on exact tie, smaller group index wins.
// Group order implies element order: g < g'  =>  g*4+c < g'*4+c' for any c,c',
// so first-occurrence argmax is preserved without tracking the component.
__device__ __forceinline__ void comb(float& m, int& g, float om, int og) {
    if (om > m || (om == m && og < g)) { m = om; g = og; }
}

// Deferred-position update: fmax tree (independent of accumulator chain)
// + one cmp + 2 cndmask. Component resolved once per block at the end.
__device__ __forceinline__ void upd_group(float& m, int& g, f32x4 a, int j) {
    const float ma = fmaxf(fmaxf(a.x, a.y), fmaxf(a.z, a.w));
    if (ma > m) { m = ma; g = j; }
}

// 8-deep rotating software pipeline, statically unrolled (named registers,
// no runtime-indexed array -> no scratch). Sustains 8 global_load_dwordx4
// in flight per wave instead of the issue-4/drain-4 pattern.
#define NT_LOAD(k) __builtin_nontemporal_load(row4 + tid + (k) * 256)
#define STEP(vv, it, nxt)                          \
    upd_group(m, g, vv, tid + (it) * 256);         \
    if ((nxt) < 31) vv = NT_LOAD(nxt);

__global__ __launch_bounds__(256, 4) void ctc_argmax_kernel(const float* __restrict__ em,
                                                            int* __restrict__ idx_out) {
    const int t   = blockIdx.x;
    const int tid = threadIdx.x;
    const f32x4* row4 = (const f32x4*)(em + (size_t)t * VOCAB);

    float m = -INFINITY;
    int   g = 0x7fffffff;

    // Per-thread groups: j = tid + it*256, it in [0,31) -> covers [0, 7936).
    // Indices ascend per thread, so strict '>' keeps first occurrence.
    f32x4 v0 = NT_LOAD(0), v1 = NT_LOAD(1), v2 = NT_LOAD(2), v3 = NT_LOAD(3);
    f32x4 v4 = NT_LOAD(4), v5 = NT_LOAD(5), v6 = NT_LOAD(6), v7 = NT_LOAD(7);

    STEP(v0,  0,  8) STEP(v1,  1,  9) STEP(v2,  2, 10) STEP(v3,  3, 11)
    STEP(v4,  4, 12) STEP(v5,  5, 13) STEP(v6,  6, 14) STEP(v7,  7, 15)
    STEP(v0,  8, 16) STEP(v1,  9, 17) STEP(v2, 10, 18) STEP(v3, 11, 19)
    STEP(v4, 12, 20) STEP(v5, 13, 21) STEP(v6, 14, 22) STEP(v7, 15, 23)
    STEP(v0, 16, 24) STEP(v1, 17, 25) STEP(v2, 18, 26) STEP(v3, 19, 27)
    STEP(v4, 20, 28) STEP(v5, 21, 29) STEP(v6, 22, 30) STEP(v7, 23, 31)
    STEP(v0, 24, 99) STEP(v1, 25, 99) STEP(v2, 26, 99) STEP(v3, 27, 99)
    STEP(v4, 28, 99) STEP(v5, 29, 99) STEP(v6, 30, 99)

    // Tail: groups [7936, 8000) -- highest indices, processed last (tie-safe).
    if (tid < 64) {
        const f32x4 tv = __builtin_nontemporal_load(row4 + 7936 + tid);
        upd_group(m, g, tv, 7936 + tid);
    }

    // 64-lane wave reduction on (max, group)
    #pragma unroll
    for (int off = 32; off > 0; off >>= 1) {
        const float om = __shfl_down(m, off, 64);
        const int   og = __shfl_down(g, off, 64);
        comb(m, g, om, og);
    }

    __shared__ float sm[4];
    __shared__ int   sg[4];
    const int lane = tid & 63;
    const int wave = tid >> 6;
    if (lane == 0) { sm[wave] = m; sg[wave] = g; }
    __syncthreads();
    if (tid == 0) {
        #pragma unroll
        for (int w = 1; w < 4; ++w) comb(m, g, sm[w], sg[w]);
        // Resolve winning component: one 16B reload + ordered compares.
        // fmaxf returns one of its inputs bit-exactly, so == matches.
        const f32x4 win = *(row4 + g);
        const int c = (win.x == m) ? 0 : (win.y == m) ? 1 : (win.z == m) ? 2 : 3;
        idx_out[t] = g * 4 + c;
    }
}

__global__ __launch_bounds__(1024) void ctc_compact_kernel(const int* __restrict__ idx,
                                                           int* __restrict__ out) {
    __shared__ int wsum[16];
    const int tid  = threadIdx.x;
    const int base = tid * 4;

    int v[4], keep[4];
    const int prev0 = (base == 0) ? -1 : idx[base - 1];  // sentinel: t=0 always first-of-run
    int cnt = 0;
    #pragma unroll
    for (int k = 0; k < 4; ++k) {
        v[k] = idx[base + k];
        const int p = (k == 0) ? prev0 : v[k - 1];
        keep[k] = (v[k] != p && v[k] != 0) ? 1 : 0;
        cnt += keep[k];
    }

    // inclusive scan of per-thread counts within each 64-lane wave
    const int lane = tid & 63;
    const int wave = tid >> 6;
    int incl = cnt;
    #pragma unroll
    for (int off = 1; off < 64; off <<= 1) {
        int n = __shfl_up(incl, off, 64);
        if (lane >= off) incl += n;
    }
    if (lane == 63) wsum[wave] = incl;

    // fill padded output with -1 (d_out is re-poisoned each call)
    #pragma unroll
    for (int k = 0; k < 4; ++k) out[base + k] = -1;
    __syncthreads();

    // scan the 16 wave totals in wave 0
    if (wave == 0) {
        int s = (lane < 16) ? wsum[lane] : 0;
        #pragma unroll
        for (int off = 1; off < 16; off <<= 1) {
            int n = __shfl_up(s, off, 64);
            if (lane >= off) s += n;
        }
        if (lane < 16) wsum[lane] = s;
    }
    __syncthreads();

    const int waveoff = (wave == 0) ? 0 : wsum[wave - 1];
    int pos = waveoff + incl - cnt;  // exclusive prefix for this thread
    #pragma unroll
    for (int k = 0; k < 4; ++k) {
        if (keep[k]) out[pos++] = v[k];
    }
    if (tid == 0) out[T_STEPS] = wsum[15];  // count
}

extern "C" void kernel_launch(void* const* d_in, const int* in_sizes, int n_in,
                              void* d_out, int out_size, void* d_ws, size_t ws_size,
                              hipStream_t stream) {
    const float* em  = (const float*)d_in[0];
    int*         out = (int*)d_out;          // [4097] int32: padded[4096], count
    int*         idx = (int*)d_ws;           // [4096] int32 scratch

    ctc_argmax_kernel<<<dim3(T_STEPS), dim3(256), 0, stream>>>(em, idx);
    ctc_compact_kernel<<<dim3(1), dim3(1024), 0, stream>>>(idx, out);
}